// Round 3
// baseline (197.211 us; speedup 1.0000x reference)
//
#include <hip/hip_runtime.h>

#define NEG_INF -1000000000.0f

typedef __attribute__((ext_vector_type(8))) short bf16x8;
typedef __attribute__((ext_vector_type(4))) float f32x4;

__device__ __forceinline__ unsigned short f2bf(float x) {
    unsigned int u = __float_as_uint(x);
    u += 0x7FFFu + ((u >> 16) & 1u);        // round-to-nearest-even
    return (unsigned short)(u >> 16);
}
__device__ __forceinline__ float bf2f(unsigned short s) {
    return __uint_as_float(((unsigned int)s) << 16);
}

// ---------------------------------------------------------------------------
// WbT[n][k] = bf16(W[k][n])  (256x256)
// ---------------------------------------------------------------------------
__global__ __launch_bounds__(256) void cast_wt(const float* __restrict__ W,
                                               short* __restrict__ WbT) {
    const int n = blockIdx.x, k = threadIdx.x;
    WbT[n * 256 + k] = (short)f2bf(W[k * 256 + n]);
}

// ---------------------------------------------------------------------------
// c1[k] = sum_o W[k][o] a1[o];  c2 likewise (a2 = a+256). Wave per k-row.
// ---------------------------------------------------------------------------
__global__ __launch_bounds__(256) void c12_kernel(const float* __restrict__ W,
                                                  const float* __restrict__ a,
                                                  float* __restrict__ c) {
    const int wid = threadIdx.x >> 6, lane = threadIdx.x & 63;
    const int k = blockIdx.x * 4 + wid;
    float4 wv = *(const float4*)(W + k * 256 + lane * 4);
    float4 a1 = *(const float4*)(a + lane * 4);
    float4 a2 = *(const float4*)(a + 256 + lane * 4);
    float s1 = wv.x * a1.x + wv.y * a1.y + wv.z * a1.z + wv.w * a1.w;
    float s2 = wv.x * a2.x + wv.y * a2.y + wv.z * a2.z + wv.w * a2.w;
#pragma unroll
    for (int off = 32; off; off >>= 1) {
        s1 += __shfl_xor(s1, off);
        s2 += __shfl_xor(s2, off);
    }
    if (lane == 0) { c[k] = s1; c[256 + k] = s2; }
}

// ---------------------------------------------------------------------------
// f1[i] = h[i,:] . c1 ; f2[i] = h[i,:] . c2.  Wave per node, fp32 exact-ish.
// ---------------------------------------------------------------------------
__global__ __launch_bounds__(256) void f12_kernel(const float* __restrict__ h,
                                                  const float* __restrict__ c,
                                                  float* __restrict__ f1,
                                                  float* __restrict__ f2) {
    const int wid = threadIdx.x >> 6, lane = threadIdx.x & 63;
    const int i = blockIdx.x * 4 + wid;
    float4 hv = *(const float4*)(h + (size_t)i * 256 + lane * 4);
    float4 c1 = *(const float4*)(c + lane * 4);
    float4 c2 = *(const float4*)(c + 256 + lane * 4);
    float s1 = hv.x * c1.x + hv.y * c1.y + hv.z * c1.z + hv.w * c1.w;
    float s2 = hv.x * c2.x + hv.y * c2.y + hv.z * c2.z + hv.w * c2.w;
#pragma unroll
    for (int off = 32; off; off >>= 1) {
        s1 += __shfl_xor(s1, off);
        s2 += __shfl_xor(s2, off);
    }
    if (lane == 0) { f1[i] = s1; f2[i] = s2; }
}

// ---------------------------------------------------------------------------
// WhT[b][f][j] = bf16( (h @ W)[b,j,f] ) via MFMA 16x16x32.
// Block: 16 nodes x 256 f. Wave w owns f-slice w*64..+63. Grid 1024.
// ---------------------------------------------------------------------------
__global__ __launch_bounds__(256, 4) void wh_gemm(const float* __restrict__ h,
                                                  const short* __restrict__ WbT,
                                                  short* __restrict__ WhT) {
    const int t = threadIdx.x;
    const int wid = t >> 6, lane = t & 63;
    const int quad = lane >> 4, l15 = lane & 15;
    const int m0 = blockIdx.x * 16;

    f32x4 acc[4] = {};

#pragma unroll
    for (int kt = 0; kt < 8; ++kt) {
        const int k0 = kt * 32;
        const float* p = h + (size_t)(m0 + l15) * 256 + k0 + quad * 8;
        float4 x = *(const float4*)p, y = *(const float4*)(p + 4);
        bf16x8 av;
        av[0] = (short)f2bf(x.x); av[1] = (short)f2bf(x.y);
        av[2] = (short)f2bf(x.z); av[3] = (short)f2bf(x.w);
        av[4] = (short)f2bf(y.x); av[5] = (short)f2bf(y.y);
        av[6] = (short)f2bf(y.z); av[7] = (short)f2bf(y.w);
#pragma unroll
        for (int ft = 0; ft < 4; ++ft) {
            const int f = wid * 64 + ft * 16 + l15;
            bf16x8 bv = *(const bf16x8*)(WbT + (size_t)f * 256 + k0 + quad * 8);
            acc[ft] = __builtin_amdgcn_mfma_f32_16x16x32_bf16(av, bv, acc[ft], 0, 0, 0);
        }
    }

    // C: row(m)=quad*4+reg, col(n=f)=l15. Store transposed bf16: WhT[b][f][il].
    const int b = m0 >> 10;
    const int il0 = (m0 & 1023) + quad * 4;
#pragma unroll
    for (int ft = 0; ft < 4; ++ft) {
        const int f = wid * 64 + ft * 16 + l15;
        ushort4 pk;
        pk.x = f2bf(acc[ft][0]);
        pk.y = f2bf(acc[ft][1]);
        pk.z = f2bf(acc[ft][2]);
        pk.w = f2bf(acc[ft][3]);
        *(ushort4*)(WhT + ((size_t)b << 18) + (size_t)f * 1024 + il0) = pk;
    }
}

// ---------------------------------------------------------------------------
// Flash-style single-pass attention + aggregation.
// Block: b=blockIdx.y, 16 i-rows at i0=blockIdx.x*16. 4 waves, grid (64,16).
// Wave w: f-slice w*64..+63, acc[4 f-tiles] (16x16 frags).
// Scores: wave w owns rows 4w+quad; 16 lanes/row, 8 j each (2x int4 groups).
// adj prefetched one 128-j tile ahead into registers.
// ---------------------------------------------------------------------------
__global__ __launch_bounds__(256, 4) void attn_kernel(const short* __restrict__ WhT,
                                                      const int* __restrict__ adj,
                                                      const float* __restrict__ f1g,
                                                      const float* __restrict__ f2g,
                                                      float* __restrict__ out) {
    __shared__ float s_f2[1024];
    __shared__ short P[2][16][136];     // p tile, bf16, A-frag layout
    __shared__ float s_alpha[2][16];
    __shared__ float s_l[16];

    const int t = threadIdx.x;
    const int b = blockIdx.y;
    const int i0 = blockIdx.x * 16;
    const int wid = t >> 6, lane = t & 63;
    const int quad = lane >> 4, l15 = lane & 15;

    *(float4*)&s_f2[t * 4] = *(const float4*)&f2g[(b << 10) + t * 4];

    const int row = wid * 4 + quad;               // 0..15: row this lane scores
    const float f1r = f1g[(b << 10) + i0 + row];
    const int* arow = adj + (size_t)((b << 10) + i0 + row) * 1024;
    const short* whb = WhT + ((size_t)b << 18);

    // prefetch adj tile 0: j = l15*4 + 64*c, c in {0,1}
    int4 pa0 = *(const int4*)(arow + l15 * 4);
    int4 pa1 = *(const int4*)(arow + 64 + l15 * 4);

    float m_run = -3.0e38f, l_run = 0.0f;
    f32x4 acc[4] = {};

    __syncthreads();

    int buf = 0;
    for (int jt = 0; jt < 8; ++jt, buf ^= 1) {
        const int j0 = jt * 128;
        const int4 cur0 = pa0, cur1 = pa1;
        if (jt < 7) {                              // prefetch next tile
            pa0 = *(const int4*)(arow + j0 + 128 + l15 * 4);
            pa1 = *(const int4*)(arow + j0 + 192 + l15 * 4);
        }

        // ---- scores for rows [i0..i0+16) x j-tile [j0..j0+128)
        float ev[8];
        float tmax = -3.0e38f;
        {
            float4 fv = *(const float4*)&s_f2[j0 + l15 * 4];
            float x0 = f1r + fv.x, x1 = f1r + fv.y, x2 = f1r + fv.z, x3 = f1r + fv.w;
            ev[0] = cur0.x ? fmaxf(x0, 0.2f * x0) : NEG_INF;
            ev[1] = cur0.y ? fmaxf(x1, 0.2f * x1) : NEG_INF;
            ev[2] = cur0.z ? fmaxf(x2, 0.2f * x2) : NEG_INF;
            ev[3] = cur0.w ? fmaxf(x3, 0.2f * x3) : NEG_INF;
            fv = *(const float4*)&s_f2[j0 + 64 + l15 * 4];
            x0 = f1r + fv.x; x1 = f1r + fv.y; x2 = f1r + fv.z; x3 = f1r + fv.w;
            ev[4] = cur1.x ? fmaxf(x0, 0.2f * x0) : NEG_INF;
            ev[5] = cur1.y ? fmaxf(x1, 0.2f * x1) : NEG_INF;
            ev[6] = cur1.z ? fmaxf(x2, 0.2f * x2) : NEG_INF;
            ev[7] = cur1.w ? fmaxf(x3, 0.2f * x3) : NEG_INF;
#pragma unroll
            for (int q = 0; q < 8; ++q) tmax = fmaxf(tmax, ev[q]);
        }
        tmax = fmaxf(tmax, __shfl_xor(tmax, 1));
        tmax = fmaxf(tmax, __shfl_xor(tmax, 2));
        tmax = fmaxf(tmax, __shfl_xor(tmax, 4));
        tmax = fmaxf(tmax, __shfl_xor(tmax, 8));
        const float m_new = fmaxf(m_run, tmax);
        const float alpha = __expf(m_run - m_new);
        m_run = m_new;

        ushort4 pk0, pk1;
        pk0.x = f2bf(__expf(ev[0] - m_new)); pk0.y = f2bf(__expf(ev[1] - m_new));
        pk0.z = f2bf(__expf(ev[2] - m_new)); pk0.w = f2bf(__expf(ev[3] - m_new));
        pk1.x = f2bf(__expf(ev[4] - m_new)); pk1.y = f2bf(__expf(ev[5] - m_new));
        pk1.z = f2bf(__expf(ev[6] - m_new)); pk1.w = f2bf(__expf(ev[7] - m_new));
        float rsum = bf2f(pk0.x) + bf2f(pk0.y) + bf2f(pk0.z) + bf2f(pk0.w)
                   + bf2f(pk1.x) + bf2f(pk1.y) + bf2f(pk1.z) + bf2f(pk1.w);
        *(ushort4*)&P[buf][row][l15 * 4] = pk0;
        *(ushort4*)&P[buf][row][64 + l15 * 4] = pk1;
        rsum += __shfl_xor(rsum, 1);
        rsum += __shfl_xor(rsum, 2);
        rsum += __shfl_xor(rsum, 4);
        rsum += __shfl_xor(rsum, 8);
        l_run = l_run * alpha + rsum;
        if (l15 == 0) s_alpha[buf][row] = alpha;

        __syncthreads();   // P[buf] + s_alpha[buf] visible to all waves

        // ---- rescale accumulators by this tile's alpha (per C-frag row)
        float4 al = *(const float4*)&s_alpha[buf][quad * 4];
#pragma unroll
        for (int ft = 0; ft < 4; ++ft) {
            acc[ft][0] *= al.x; acc[ft][1] *= al.y;
            acc[ft][2] *= al.z; acc[ft][3] *= al.w;
        }

        // ---- MFMA over this tile's 128 k (4 steps of 32)
#pragma unroll
        for (int kt = 0; kt < 4; ++kt) {
            bf16x8 a0 = *(const bf16x8*)&P[buf][l15][kt * 32 + quad * 8];
#pragma unroll
            for (int ft = 0; ft < 4; ++ft) {
                const short* bp = whb + (size_t)(wid * 64 + ft * 16 + l15) * 1024
                                  + j0 + kt * 32 + quad * 8;
                bf16x8 bv = *(const bf16x8*)bp;
                acc[ft] = __builtin_amdgcn_mfma_f32_16x16x32_bf16(a0, bv, acc[ft], 0, 0, 0);
            }
        }
        // no second barrier: next tile writes the other P/alpha buffer.
    }

    if (l15 == 0) s_l[row] = l_run;
    __syncthreads();

    float4 lv = *(const float4*)&s_l[quad * 4];
    const float n0 = 1.0f / lv.x, n1 = 1.0f / lv.y, n2 = 1.0f / lv.z, n3 = 1.0f / lv.w;

#pragma unroll
    for (int ft = 0; ft < 4; ++ft) {
        const int f = wid * 64 + ft * 16 + l15;
        float* op = out + (size_t)((b << 10) + i0 + quad * 4) * 256 + f;
        op[0]   = acc[ft][0] * n0;
        op[256] = acc[ft][1] * n1;
        op[512] = acc[ft][2] * n2;
        op[768] = acc[ft][3] * n3;
    }
}

// ---------------------------------------------------------------------------
extern "C" void kernel_launch(void* const* d_in, const int* in_sizes, int n_in,
                              void* d_out, int out_size, void* d_ws, size_t ws_size,
                              hipStream_t stream) {
    const float* h   = (const float*)d_in[0];
    const int*   adj = (const int*)d_in[1];
    const float* W   = (const float*)d_in[2];
    const float* a   = (const float*)d_in[3];
    float* out = (float*)d_out;

    short* WbT = (short*)d_ws;                    // 256*256 bf16     = 128 KB
    short* WhT = WbT + 65536;                     // 16*256*1024 bf16 = 8 MB
    float* f1  = (float*)(WhT + 16 * 1024 * 256); // 16384 f32
    float* f2  = f1 + 16384;                      // 16384 f32
    float* c   = f2 + 16384;                      // 512 f32 (c1|c2)

    cast_wt<<<256, 256, 0, stream>>>(W, WbT);
    c12_kernel<<<64, 256, 0, stream>>>(W, a, c);
    f12_kernel<<<4096, 256, 0, stream>>>(h, c, f1, f2);
    wh_gemm<<<1024, 256, 0, stream>>>(h, WbT, WhT);
    attn_kernel<<<dim3(64, 16), 256, 0, stream>>>(WhT, adj, f1, f2, out);
}

// Round 4
// 195.136 us; speedup vs baseline: 1.0106x; 1.0106x over previous
//
#include <hip/hip_runtime.h>

#define NEG_INF -1000000000.0f

typedef __attribute__((ext_vector_type(8))) short bf16x8;
typedef __attribute__((ext_vector_type(4))) float f32x4;

__device__ __forceinline__ unsigned short f2bf(float x) {
    unsigned int u = __float_as_uint(x);
    u += 0x7FFFu + ((u >> 16) & 1u);        // round-to-nearest-even
    return (unsigned short)(u >> 16);
}
__device__ __forceinline__ float bf2f(unsigned short s) {
    return __uint_as_float(((unsigned int)s) << 16);
}

// ---------------------------------------------------------------------------
// WbT[n][k] = bf16(W[k][n]) via coalesced 32x32 LDS transpose. Grid 64.
// ---------------------------------------------------------------------------
__global__ __launch_bounds__(256) void cast_wt(const float* __restrict__ W,
                                               short* __restrict__ WbT) {
    __shared__ float tile[32][33];
    const int t = threadIdx.x;
    const int bx = blockIdx.x & 7, by = blockIdx.x >> 3;
    const int r0 = by * 32, c0 = bx * 32;
    const int lr = t >> 5, lc = t & 31;
#pragma unroll
    for (int q = 0; q < 4; ++q)
        tile[q * 8 + lr][lc] = W[(r0 + q * 8 + lr) * 256 + c0 + lc];
    __syncthreads();
#pragma unroll
    for (int q = 0; q < 4; ++q)
        WbT[(c0 + q * 8 + lr) * 256 + r0 + lc] = (short)f2bf(tile[lc][q * 8 + lr]);
}

// ---------------------------------------------------------------------------
// c1[k] = sum_o W[k][o] a1[o];  c2 likewise. Wave per k-row.
// ---------------------------------------------------------------------------
__global__ __launch_bounds__(256) void c12_kernel(const float* __restrict__ W,
                                                  const float* __restrict__ a,
                                                  float* __restrict__ c) {
    const int wid = threadIdx.x >> 6, lane = threadIdx.x & 63;
    const int k = blockIdx.x * 4 + wid;
    float4 wv = *(const float4*)(W + k * 256 + lane * 4);
    float4 a1 = *(const float4*)(a + lane * 4);
    float4 a2 = *(const float4*)(a + 256 + lane * 4);
    float s1 = wv.x * a1.x + wv.y * a1.y + wv.z * a1.z + wv.w * a1.w;
    float s2 = wv.x * a2.x + wv.y * a2.y + wv.z * a2.z + wv.w * a2.w;
#pragma unroll
    for (int off = 32; off; off >>= 1) {
        s1 += __shfl_xor(s1, off);
        s2 += __shfl_xor(s2, off);
    }
    if (lane == 0) { c[k] = s1; c[256 + k] = s2; }
}

// ---------------------------------------------------------------------------
// f1[i] = h[i,:] . c1 ; f2[i] = h[i,:] . c2.  Wave per node (fp32).
// ---------------------------------------------------------------------------
__global__ __launch_bounds__(256) void f12_kernel(const float* __restrict__ h,
                                                  const float* __restrict__ c,
                                                  float* __restrict__ f1,
                                                  float* __restrict__ f2) {
    const int wid = threadIdx.x >> 6, lane = threadIdx.x & 63;
    const int i = blockIdx.x * 4 + wid;
    float4 hv = *(const float4*)(h + (size_t)i * 256 + lane * 4);
    float4 c1 = *(const float4*)(c + lane * 4);
    float4 c2 = *(const float4*)(c + 256 + lane * 4);
    float s1 = hv.x * c1.x + hv.y * c1.y + hv.z * c1.z + hv.w * c1.w;
    float s2 = hv.x * c2.x + hv.y * c2.y + hv.z * c2.z + hv.w * c2.w;
#pragma unroll
    for (int off = 32; off; off >>= 1) {
        s1 += __shfl_xor(s1, off);
        s2 += __shfl_xor(s2, off);
    }
    if (lane == 0) { f1[i] = s1; f2[i] = s2; }
}

// ---------------------------------------------------------------------------
// WhT[b][f][j] = bf16( (h @ W)[b,j,f] ) via MFMA 16x16x32. 16 nodes/block.
// ---------------------------------------------------------------------------
__global__ __launch_bounds__(256, 4) void wh_gemm(const float* __restrict__ h,
                                                  const short* __restrict__ WbT,
                                                  short* __restrict__ WhT) {
    const int t = threadIdx.x;
    const int wid = t >> 6, lane = t & 63;
    const int quad = lane >> 4, l15 = lane & 15;
    const int m0 = blockIdx.x * 16;

    f32x4 acc[4] = {};

#pragma unroll
    for (int kt = 0; kt < 8; ++kt) {
        const int k0 = kt * 32;
        const float* p = h + (size_t)(m0 + l15) * 256 + k0 + quad * 8;
        float4 x = *(const float4*)p, y = *(const float4*)(p + 4);
        bf16x8 av;
        av[0] = (short)f2bf(x.x); av[1] = (short)f2bf(x.y);
        av[2] = (short)f2bf(x.z); av[3] = (short)f2bf(x.w);
        av[4] = (short)f2bf(y.x); av[5] = (short)f2bf(y.y);
        av[6] = (short)f2bf(y.z); av[7] = (short)f2bf(y.w);
#pragma unroll
        for (int ft = 0; ft < 4; ++ft) {
            const int f = wid * 64 + ft * 16 + l15;
            bf16x8 bv = *(const bf16x8*)(WbT + (size_t)f * 256 + k0 + quad * 8);
            acc[ft] = __builtin_amdgcn_mfma_f32_16x16x32_bf16(av, bv, acc[ft], 0, 0, 0);
        }
    }

    const int b = m0 >> 10;
    const int il0 = (m0 & 1023) + quad * 4;
#pragma unroll
    for (int ft = 0; ft < 4; ++ft) {
        const int f = wid * 64 + ft * 16 + l15;
        ushort4 pk;
        pk.x = f2bf(acc[ft][0]);
        pk.y = f2bf(acc[ft][1]);
        pk.z = f2bf(acc[ft][2]);
        pk.w = f2bf(acc[ft][3]);
        *(ushort4*)(WhT + ((size_t)b << 18) + (size_t)f * 1024 + il0) = pk;
    }
}

// ---------------------------------------------------------------------------
// Stats pass: per row i -> m = max_j e_ij, inv_l = 1/sum_j exp(e_ij - m),
// plus adj repacked to a bitmask (16 j per ushort). Wave per row, no barriers.
// ---------------------------------------------------------------------------
__global__ __launch_bounds__(256) void stats_kernel(const int* __restrict__ adj,
                                                    const float* __restrict__ f1g,
                                                    const float* __restrict__ f2g,
                                                    unsigned short* __restrict__ bm,
                                                    float2* __restrict__ msc) {
    const int wid = threadIdx.x >> 6, lane = threadIdx.x & 63;
    const int gid = blockIdx.x * 4 + wid;          // global row 0..16383
    const int b = gid >> 10;
    const int* arow = adj + (size_t)gid * 1024;
    const float* f2b = f2g + (b << 10);
    const float f1r = f1g[gid];
    const int j0 = lane * 16;

    float e[16];
    unsigned int bits = 0;
#pragma unroll
    for (int r = 0; r < 4; ++r) {
        int4 av = *(const int4*)(arow + j0 + r * 4);
        float4 fv = *(const float4*)(f2b + j0 + r * 4);
        float x0 = f1r + fv.x, x1 = f1r + fv.y, x2 = f1r + fv.z, x3 = f1r + fv.w;
        e[r * 4 + 0] = av.x ? fmaxf(x0, 0.2f * x0) : -3.0e38f;
        e[r * 4 + 1] = av.y ? fmaxf(x1, 0.2f * x1) : -3.0e38f;
        e[r * 4 + 2] = av.z ? fmaxf(x2, 0.2f * x2) : -3.0e38f;
        e[r * 4 + 3] = av.w ? fmaxf(x3, 0.2f * x3) : -3.0e38f;
        bits |= (av.x ? 1u : 0u) << (r * 4 + 0);
        bits |= (av.y ? 1u : 0u) << (r * 4 + 1);
        bits |= (av.z ? 1u : 0u) << (r * 4 + 2);
        bits |= (av.w ? 1u : 0u) << (r * 4 + 3);
    }
    float m = e[0];
#pragma unroll
    for (int q = 1; q < 16; ++q) m = fmaxf(m, e[q]);
#pragma unroll
    for (int off = 32; off; off >>= 1) m = fmaxf(m, __shfl_xor(m, off));

    float l = 0.f;
#pragma unroll
    for (int q = 0; q < 16; ++q) l += __expf(e[q] - m);   // exp(-3e38-m) -> 0
#pragma unroll
    for (int off = 32; off; off >>= 1) l += __shfl_xor(l, off);

    bm[(size_t)gid * 64 + lane] = (unsigned short)bits;
    if (lane == 0) msc[gid] = make_float2(m, 1.0f / l);
}

// ---------------------------------------------------------------------------
// Aggregation: out[i,:] = sum_j p_ij * Wh[j,:], p precomputed-normalizable.
// Block: 32 i-rows x 256 f, 4 waves (wave w -> f-slice w*64..+63).
// One barrier per 128-j tile; P double-buffered; B-frags batch-loaded after
// the barrier (fine-grained vmcnt); no cross-tile softmax dependency.
// ---------------------------------------------------------------------------
__global__ __launch_bounds__(256, 2) void agg_kernel(const short* __restrict__ WhT,
                                                     const unsigned short* __restrict__ bm,
                                                     const float* __restrict__ f1g,
                                                     const float* __restrict__ f2g,
                                                     const float2* __restrict__ msc,
                                                     float* __restrict__ out) {
    __shared__ float s_f2[1024];
    __shared__ short P[2][32][136];    // bf16 p-tile, A-frag layout

    const int t = threadIdx.x;
    const int b = blockIdx.y;
    const int i0 = blockIdx.x * 32;
    const int wid = t >> 6, lane = t & 63;
    const int quad = lane >> 4, l15 = lane & 15;

    *(float4*)&s_f2[t * 4] = *(const float4*)&f2g[(b << 10) + t * 4];

    // score role: 8 threads per row, 16 j each
    const int srow = t >> 3, l8 = t & 7;
    const int gi = (b << 10) + i0 + srow;
    const float2 ms = msc[gi];
    const float f1r = f1g[gi];
    const unsigned short* brow = bm + (size_t)gi * 64;
    const short* whb = WhT + ((size_t)b << 18);

    unsigned int pb = brow[l8];        // bitmask prefetch, tile 0
    f32x4 acc[2][4] = {};

    __syncthreads();

    int buf = 0;
    for (int jt = 0; jt < 8; ++jt, buf ^= 1) {
        const int j0 = jt * 128;
        const unsigned int bits = pb;

        // ---- scores -> P[buf]
#pragma unroll
        for (int g = 0; g < 4; ++g) {
            float4 fv = *(const float4*)&s_f2[j0 + l8 * 16 + g * 4];
            float x0 = f1r + fv.x, x1 = f1r + fv.y, x2 = f1r + fv.z, x3 = f1r + fv.w;
            float e0 = fmaxf(x0, 0.2f * x0), e1 = fmaxf(x1, 0.2f * x1);
            float e2 = fmaxf(x2, 0.2f * x2), e3 = fmaxf(x3, 0.2f * x3);
            ushort4 pk;
            pk.x = ((bits >> (g * 4 + 0)) & 1u) ? f2bf(__expf(e0 - ms.x) * ms.y) : 0;
            pk.y = ((bits >> (g * 4 + 1)) & 1u) ? f2bf(__expf(e1 - ms.x) * ms.y) : 0;
            pk.z = ((bits >> (g * 4 + 2)) & 1u) ? f2bf(__expf(e2 - ms.x) * ms.y) : 0;
            pk.w = ((bits >> (g * 4 + 3)) & 1u) ? f2bf(__expf(e3 - ms.x) * ms.y) : 0;
            *(ushort4*)&P[buf][srow][l8 * 16 + g * 4] = pk;
        }
        if (jt < 7) pb = brow[(jt + 1) * 8 + l8];

        __syncthreads();   // P[buf] ready; double-buffer makes 1 barrier/tile safe

        // ---- B-frags for this tile: 16 independent loads, then MFMA
        bf16x8 Bv[4][4];
#pragma unroll
        for (int kt = 0; kt < 4; ++kt)
#pragma unroll
            for (int ft = 0; ft < 4; ++ft)
                Bv[kt][ft] = *(const bf16x8*)(whb
                    + (size_t)(wid * 64 + ft * 16 + l15) * 1024
                    + j0 + kt * 32 + quad * 8);

#pragma unroll
        for (int kt = 0; kt < 4; ++kt) {
            bf16x8 a0 = *(const bf16x8*)&P[buf][l15][kt * 32 + quad * 8];
            bf16x8 a1 = *(const bf16x8*)&P[buf][16 + l15][kt * 32 + quad * 8];
#pragma unroll
            for (int ft = 0; ft < 4; ++ft) {
                acc[0][ft] = __builtin_amdgcn_mfma_f32_16x16x32_bf16(a0, Bv[kt][ft], acc[0][ft], 0, 0, 0);
                acc[1][ft] = __builtin_amdgcn_mfma_f32_16x16x32_bf16(a1, Bv[kt][ft], acc[1][ft], 0, 0, 0);
            }
        }
    }

    // ---- epilogue: 1/l already folded into p, direct store
#pragma unroll
    for (int rt = 0; rt < 2; ++rt) {
#pragma unroll
        for (int ft = 0; ft < 4; ++ft) {
            const int f = wid * 64 + ft * 16 + l15;
            float* op = out + (size_t)((b << 10) + i0 + rt * 16 + quad * 4) * 256 + f;
            op[0]   = acc[rt][ft][0];
            op[256] = acc[rt][ft][1];
            op[512] = acc[rt][ft][2];
            op[768] = acc[rt][ft][3];
        }
    }
}

// ---------------------------------------------------------------------------
extern "C" void kernel_launch(void* const* d_in, const int* in_sizes, int n_in,
                              void* d_out, int out_size, void* d_ws, size_t ws_size,
                              hipStream_t stream) {
    const float* h   = (const float*)d_in[0];
    const int*   adj = (const int*)d_in[1];
    const float* W   = (const float*)d_in[2];
    const float* a   = (const float*)d_in[3];
    float* out = (float*)d_out;

    short* WbT = (short*)d_ws;                      // 128 KB
    short* WhT = WbT + 65536;                       // 8 MB
    float* f1  = (float*)(WhT + 16 * 1024 * 256);   // 64 KB
    float* f2  = f1 + 16384;                        // 64 KB
    float* c   = f2 + 16384;                        // 2 KB
    float2* msc = (float2*)(c + 512);               // 128 KB
    unsigned short* bmsk = (unsigned short*)(msc + 16384); // 2 MB

    cast_wt<<<64, 256, 0, stream>>>(W, WbT);
    c12_kernel<<<64, 256, 0, stream>>>(W, a, c);
    f12_kernel<<<4096, 256, 0, stream>>>(h, c, f1, f2);
    wh_gemm<<<1024, 256, 0, stream>>>(h, WbT, WhT);
    stats_kernel<<<4096, 256, 0, stream>>>(adj, f1, f2, bmsk, msc);
    agg_kernel<<<dim3(32, 16), 256, 0, stream>>>(WhT, bmsk, f1, f2, msc, out);
}

// Round 6
// 178.058 us; speedup vs baseline: 1.1076x; 1.0959x over previous
//
#include <hip/hip_runtime.h>

typedef __attribute__((ext_vector_type(8))) short bf16x8;
typedef __attribute__((ext_vector_type(4))) float f32x4;

__device__ __forceinline__ unsigned short f2bf(float x) {
    unsigned int u = __float_as_uint(x);
    u += 0x7FFFu + ((u >> 16) & 1u);        // round-to-nearest-even
    return (unsigned short)(u >> 16);
}

// async global->LDS, 16B per lane; LDS dest = wave-uniform base + lane*16,
// so per-thread lds ptr must be base + t*16 with lane-contiguous layout.
__device__ __forceinline__ void gl_lds16(const void* g, void* l) {
    __builtin_amdgcn_global_load_lds(
        (__attribute__((address_space(1))) void*)((void*)g),
        (__attribute__((address_space(3))) void*)l, 16, 0, 0);
}

// ---------------------------------------------------------------------------
// prep: WbT[n][k] = bf16(W[k][n]) via coalesced 32x32 LDS transpose. Grid 64.
// ---------------------------------------------------------------------------
__global__ __launch_bounds__(256) void prep(const float* __restrict__ W,
                                            short* __restrict__ WbT) {
    __shared__ float tile[32][33];
    const int t = threadIdx.x;
    const int bx = blockIdx.x & 7, by = blockIdx.x >> 3;
    const int r0 = by * 32, c0 = bx * 32;
    const int lr = t >> 5, lc = t & 31;
#pragma unroll
    for (int q = 0; q < 4; ++q)
        tile[q * 8 + lr][lc] = W[(r0 + q * 8 + lr) * 256 + c0 + lc];
    __syncthreads();
#pragma unroll
    for (int q = 0; q < 4; ++q)
        WbT[(c0 + q * 8 + lr) * 256 + r0 + lc] = (short)f2bf(tile[lc][q * 8 + lr]);
}

// ---------------------------------------------------------------------------
// wh_f12: WhT[b][f][j] = bf16((h@W)[b,j,f]) via MFMA (16 nodes/block), and
// f1[i] = Wh[i,:].a1, f2[i] = Wh[i,:].a2 reduced from the fp32 accumulators.
// ---------------------------------------------------------------------------
__global__ __launch_bounds__(256, 4) void wh_f12(const float* __restrict__ h,
                                                 const short* __restrict__ WbT,
                                                 const float* __restrict__ a,
                                                 short* __restrict__ WhT,
                                                 float* __restrict__ f1,
                                                 float* __restrict__ f2) {
    __shared__ float sp[2][4][16];
    const int t = threadIdx.x;
    const int wid = t >> 6, lane = t & 63;
    const int quad = lane >> 4, l15 = lane & 15;
    const int m0 = blockIdx.x * 16;

    f32x4 acc[4] = {};

#pragma unroll
    for (int kt = 0; kt < 8; ++kt) {
        const int k0 = kt * 32;
        const float* p = h + (size_t)(m0 + l15) * 256 + k0 + quad * 8;
        float4 x = *(const float4*)p, y = *(const float4*)(p + 4);
        bf16x8 av;
        av[0] = (short)f2bf(x.x); av[1] = (short)f2bf(x.y);
        av[2] = (short)f2bf(x.z); av[3] = (short)f2bf(x.w);
        av[4] = (short)f2bf(y.x); av[5] = (short)f2bf(y.y);
        av[6] = (short)f2bf(y.z); av[7] = (short)f2bf(y.w);
#pragma unroll
        for (int ft = 0; ft < 4; ++ft) {
            const int f = wid * 64 + ft * 16 + l15;
            bf16x8 bv = *(const bf16x8*)(WbT + (size_t)f * 256 + k0 + quad * 8);
            acc[ft] = __builtin_amdgcn_mfma_f32_16x16x32_bf16(av, bv, acc[ft], 0, 0, 0);
        }
    }

    // --- WhT store (C row = quad*4+reg, col f = wid*64+ft*16+l15)
    const int b = m0 >> 10;
    const int il0 = (m0 & 1023) + quad * 4;
#pragma unroll
    for (int ft = 0; ft < 4; ++ft) {
        const int f = wid * 64 + ft * 16 + l15;
        ushort4 pk;
        pk.x = f2bf(acc[ft][0]);
        pk.y = f2bf(acc[ft][1]);
        pk.z = f2bf(acc[ft][2]);
        pk.w = f2bf(acc[ft][3]);
        *(ushort4*)(WhT + ((size_t)b << 18) + (size_t)f * 1024 + il0) = pk;
    }

    // --- f1/f2 from fp32 acc: dot with a1/a2 over this wave's 64-f slice
    float a1v[4], a2v[4];
#pragma unroll
    for (int ft = 0; ft < 4; ++ft) {
        a1v[ft] = a[wid * 64 + ft * 16 + l15];
        a2v[ft] = a[256 + wid * 64 + ft * 16 + l15];
    }
    float p1[4] = {}, p2[4] = {};
#pragma unroll
    for (int ft = 0; ft < 4; ++ft)
#pragma unroll
        for (int r = 0; r < 4; ++r) {
            p1[r] += acc[ft][r] * a1v[ft];
            p2[r] += acc[ft][r] * a2v[ft];
        }
#pragma unroll
    for (int off = 1; off < 16; off <<= 1)
#pragma unroll
        for (int r = 0; r < 4; ++r) {
            p1[r] += __shfl_xor(p1[r], off);
            p2[r] += __shfl_xor(p2[r], off);
        }
    if (l15 == 0)
#pragma unroll
        for (int r = 0; r < 4; ++r) {
            sp[0][wid][quad * 4 + r] = p1[r];
            sp[1][wid][quad * 4 + r] = p2[r];
        }
    __syncthreads();
    if (t < 16) {
        f1[m0 + t] = sp[0][0][t] + sp[0][1][t] + sp[0][2][t] + sp[0][3][t];
        f2[m0 + t] = sp[1][0][t] + sp[1][1][t] + sp[1][2][t] + sp[1][3][t];
    }
}

// ---------------------------------------------------------------------------
// stats_p: wave per row. One streaming pass over adj; writes normalized
// P[b][i][j] = bf16( exp(e_ij - m_i) / l_i ). No barriers, no re-read.
// ---------------------------------------------------------------------------
__global__ __launch_bounds__(256) void stats_p(const int* __restrict__ adj,
                                               const float* __restrict__ f1g,
                                               const float* __restrict__ f2g,
                                               short* __restrict__ P) {
    const int wid = threadIdx.x >> 6, lane = threadIdx.x & 63;
    const int gid = blockIdx.x * 4 + wid;          // row 0..16383
    const int b = gid >> 10;
    const int* arow = adj + (size_t)gid * 1024;
    const float* f2b = f2g + (b << 10);
    const float f1r = f1g[gid];
    const int j0 = lane * 16;

    float e[16];
#pragma unroll
    for (int r = 0; r < 4; ++r) {
        int4 av = *(const int4*)(arow + j0 + r * 4);
        float4 fv = *(const float4*)(f2b + j0 + r * 4);
        float x0 = f1r + fv.x, x1 = f1r + fv.y, x2 = f1r + fv.z, x3 = f1r + fv.w;
        e[r * 4 + 0] = av.x ? fmaxf(x0, 0.2f * x0) : -3.0e38f;
        e[r * 4 + 1] = av.y ? fmaxf(x1, 0.2f * x1) : -3.0e38f;
        e[r * 4 + 2] = av.z ? fmaxf(x2, 0.2f * x2) : -3.0e38f;
        e[r * 4 + 3] = av.w ? fmaxf(x3, 0.2f * x3) : -3.0e38f;
    }
    float m = e[0];
#pragma unroll
    for (int q = 1; q < 16; ++q) m = fmaxf(m, e[q]);
#pragma unroll
    for (int off = 32; off; off >>= 1) m = fmaxf(m, __shfl_xor(m, off));

    float l = 0.f;
#pragma unroll
    for (int q = 0; q < 16; ++q) l += __expf(e[q] - m);
#pragma unroll
    for (int off = 32; off; off >>= 1) l += __shfl_xor(l, off);
    const float invl = 1.0f / l;

    bf16x8 v0, v1;
#pragma unroll
    for (int q = 0; q < 8; ++q) v0[q] = (short)f2bf(__expf(e[q] - m) * invl);
#pragma unroll
    for (int q = 0; q < 8; ++q) v1[q] = (short)f2bf(__expf(e[8 + q] - m) * invl);
    short* prow = P + (size_t)gid * 1024 + j0;
    *(bf16x8*)prow = v0;
    *(bf16x8*)(prow + 8) = v1;
}

// ---------------------------------------------------------------------------
// agg: out[b] = P[b] (1024x1024) @ WhT[b]^T (K-contig B). m97-style GEMM:
// 128M x 64N tile, BK=32, global_load_lds(16B) staging, 2 barriers/iter.
// Grid (8,4,16) = 512 blocks -> 2 blocks/CU.
// ---------------------------------------------------------------------------
__global__ __launch_bounds__(256, 2) void agg(const short* __restrict__ P,
                                              const short* __restrict__ WhT,
                                              float* __restrict__ out) {
    __shared__ short As[128 * 32];   // 8 KB
    __shared__ short Bs[64 * 32];    // 4 KB

    const int t = threadIdx.x;
    const int wid = t >> 6, lane = t & 63;
    const int quad = lane >> 4, l15 = lane & 15;
    const int m0 = blockIdx.x * 128, n0 = blockIdx.y * 64, b = blockIdx.z;

    const short* Pb = P + ((size_t)b << 20);
    const short* Wb = WhT + ((size_t)b << 18);

    // staging: chunk c=t -> row c>>2, short-offset (c&3)*8; lds byte = c*16
    const int ar = t >> 2, aq = (t & 3) * 8;
    const short* ga0 = Pb + (size_t)(m0 + ar) * 1024 + aq;         // As rows 0..63
    const short* ga1 = Pb + (size_t)(m0 + 64 + ar) * 1024 + aq;    // As rows 64..127
    const short* gb0 = Wb + (size_t)(n0 + ar) * 1024 + aq;         // Bs rows 0..63
    short* lA0 = As + t * 8;
    short* lA1 = As + 2048 + t * 8;
    short* lB0 = Bs + t * 8;

    f32x4 acc[2][4] = {};

    for (int k0 = 0; k0 < 1024; k0 += 32) {
        gl_lds16(ga0 + k0, lA0);
        gl_lds16(ga1 + k0, lA1);
        gl_lds16(gb0 + k0, lB0);
        __syncthreads();

        bf16x8 av[2], bv[4];
#pragma unroll
        for (int mf = 0; mf < 2; ++mf)
            av[mf] = *(const bf16x8*)(As + (wid * 32 + mf * 16 + l15) * 32 + quad * 8);
#pragma unroll
        for (int nf = 0; nf < 4; ++nf)
            bv[nf] = *(const bf16x8*)(Bs + (nf * 16 + l15) * 32 + quad * 8);
#pragma unroll
        for (int mf = 0; mf < 2; ++mf)
#pragma unroll
            for (int nf = 0; nf < 4; ++nf)
                acc[mf][nf] = __builtin_amdgcn_mfma_f32_16x16x32_bf16(av[mf], bv[nf], acc[mf][nf], 0, 0, 0);
        __syncthreads();
    }

    // epilogue: C row = quad*4+reg, col = l15 (within 16x16 frag)
#pragma unroll
    for (int mf = 0; mf < 2; ++mf) {
        const int i = m0 + wid * 32 + mf * 16 + quad * 4;
#pragma unroll
        for (int nf = 0; nf < 4; ++nf) {
            float* op = out + (size_t)((b << 10) + i) * 256 + n0 + nf * 16 + l15;
            op[0]   = acc[mf][nf][0];
            op[256] = acc[mf][nf][1];
            op[512] = acc[mf][nf][2];
            op[768] = acc[mf][nf][3];
        }
    }
}

// ---------------------------------------------------------------------------
extern "C" void kernel_launch(void* const* d_in, const int* in_sizes, int n_in,
                              void* d_out, int out_size, void* d_ws, size_t ws_size,
                              hipStream_t stream) {
    const float* h   = (const float*)d_in[0];
    const int*   adj = (const int*)d_in[1];
    const float* W   = (const float*)d_in[2];
    const float* a   = (const float*)d_in[3];
    float* out = (float*)d_out;

    short* WbT = (short*)d_ws;                       // 128 KB
    float* f1  = (float*)(WbT + 65536);              // 64 KB
    float* f2  = f1 + 16384;                         // 64 KB
    short* WhT = (short*)(f2 + 16384);               // 8 MB
    short* P   = WhT + 16 * 256 * 1024;              // 32 MB

    prep<<<64, 256, 0, stream>>>(W, WbT);
    wh_f12<<<1024, 256, 0, stream>>>(h, WbT, a, WhT, f1, f2);
    stats_p<<<4096, 256, 0, stream>>>(adj, f1, f2, P);
    agg<<<dim3(8, 4, 16), 256, 0, stream>>>(P, WhT, out);
}

// Round 7
// 165.625 us; speedup vs baseline: 1.1907x; 1.0751x over previous
//
#include <hip/hip_runtime.h>

typedef __attribute__((ext_vector_type(8))) short bf16x8;
typedef __attribute__((ext_vector_type(4))) float f32x4;

__device__ __forceinline__ unsigned short f2bf(float x) {
    unsigned int u = __float_as_uint(x);
    u += 0x7FFFu + ((u >> 16) & 1u);        // round-to-nearest-even
    return (unsigned short)(u >> 16);
}

// async global->LDS, 16B per lane; LDS dest = wave-uniform base + lane*16,
// so per-thread lds ptr must be base + t*16 with lane-contiguous layout.
__device__ __forceinline__ void gl_lds16(const void* g, void* l) {
    __builtin_amdgcn_global_load_lds(
        (__attribute__((address_space(1))) void*)((void*)g),
        (__attribute__((address_space(3))) void*)l, 16, 0, 0);
}

// ---------------------------------------------------------------------------
// prep: WbT[n][k] = bf16(W[k][n]) via coalesced 32x32 LDS transpose. Grid 64.
// ---------------------------------------------------------------------------
__global__ __launch_bounds__(256) void prep(const float* __restrict__ W,
                                            short* __restrict__ WbT) {
    __shared__ float tile[32][33];
    const int t = threadIdx.x;
    const int bx = blockIdx.x & 7, by = blockIdx.x >> 3;
    const int r0 = by * 32, c0 = bx * 32;
    const int lr = t >> 5, lc = t & 31;
#pragma unroll
    for (int q = 0; q < 4; ++q)
        tile[q * 8 + lr][lc] = W[(r0 + q * 8 + lr) * 256 + c0 + lc];
    __syncthreads();
#pragma unroll
    for (int q = 0; q < 4; ++q)
        WbT[(c0 + q * 8 + lr) * 256 + r0 + lc] = (short)f2bf(tile[lc][q * 8 + lr]);
}

// ---------------------------------------------------------------------------
// wh_f12: WhT[b][f][j] = bf16((h@W)[b,j,f]) via MFMA (16 nodes/block), and
// f1[i] = Wh[i,:].a1, f2[i] = Wh[i,:].a2 reduced from the fp32 accumulators.
// h-tile staged via LDS with coalesced loads (1 KB contiguous per instr).
// ---------------------------------------------------------------------------
__global__ __launch_bounds__(256, 4) void wh_f12(const float* __restrict__ h,
                                                 const short* __restrict__ WbT,
                                                 const float* __restrict__ a,
                                                 short* __restrict__ WhT,
                                                 float* __restrict__ f1,
                                                 float* __restrict__ f2) {
    __shared__ short hA[16][264];      // bf16 h-tile, +8 pad -> 2-way banks (free)
    __shared__ float sp[2][4][16];
    const int t = threadIdx.x;
    const int wid = t >> 6, lane = t & 63;
    const int quad = lane >> 4, l15 = lane & 15;
    const int m0 = blockIdx.x * 16;

    // --- stage h-tile: thread t -> row t>>4, cols (t&15)*16..+15 (64 B/thread)
    {
        const int r = t >> 4, c0 = (t & 15) * 16;
        const float* hp = h + (size_t)(m0 + r) * 256 + c0;
        float4 v0 = *(const float4*)(hp + 0), v1 = *(const float4*)(hp + 4);
        float4 v2 = *(const float4*)(hp + 8), v3 = *(const float4*)(hp + 12);
        bf16x8 w0, w1;
        w0[0] = (short)f2bf(v0.x); w0[1] = (short)f2bf(v0.y);
        w0[2] = (short)f2bf(v0.z); w0[3] = (short)f2bf(v0.w);
        w0[4] = (short)f2bf(v1.x); w0[5] = (short)f2bf(v1.y);
        w0[6] = (short)f2bf(v1.z); w0[7] = (short)f2bf(v1.w);
        w1[0] = (short)f2bf(v2.x); w1[1] = (short)f2bf(v2.y);
        w1[2] = (short)f2bf(v2.z); w1[3] = (short)f2bf(v2.w);
        w1[4] = (short)f2bf(v3.x); w1[5] = (short)f2bf(v3.y);
        w1[6] = (short)f2bf(v3.z); w1[7] = (short)f2bf(v3.w);
        *(bf16x8*)&hA[r][c0] = w0;
        *(bf16x8*)&hA[r][c0 + 8] = w1;
    }
    __syncthreads();

    f32x4 acc[4] = {};
#pragma unroll
    for (int kt = 0; kt < 8; ++kt) {
        const int k0 = kt * 32;
        bf16x8 av = *(const bf16x8*)&hA[l15][k0 + quad * 8];
#pragma unroll
        for (int ft = 0; ft < 4; ++ft) {
            const int f = wid * 64 + ft * 16 + l15;
            bf16x8 bv = *(const bf16x8*)(WbT + (size_t)f * 256 + k0 + quad * 8);
            acc[ft] = __builtin_amdgcn_mfma_f32_16x16x32_bf16(av, bv, acc[ft], 0, 0, 0);
        }
    }

    // --- WhT store (C row = quad*4+reg, col f = wid*64+ft*16+l15)
    const int b = m0 >> 10;
    const int il0 = (m0 & 1023) + quad * 4;
#pragma unroll
    for (int ft = 0; ft < 4; ++ft) {
        const int f = wid * 64 + ft * 16 + l15;
        ushort4 pk;
        pk.x = f2bf(acc[ft][0]);
        pk.y = f2bf(acc[ft][1]);
        pk.z = f2bf(acc[ft][2]);
        pk.w = f2bf(acc[ft][3]);
        *(ushort4*)(WhT + ((size_t)b << 18) + (size_t)f * 1024 + il0) = pk;
    }

    // --- f1/f2 from fp32 acc: dot with a1/a2 over this wave's 64-f slice
    float a1v[4], a2v[4];
#pragma unroll
    for (int ft = 0; ft < 4; ++ft) {
        a1v[ft] = a[wid * 64 + ft * 16 + l15];
        a2v[ft] = a[256 + wid * 64 + ft * 16 + l15];
    }
    float p1[4] = {}, p2[4] = {};
#pragma unroll
    for (int ft = 0; ft < 4; ++ft)
#pragma unroll
        for (int r = 0; r < 4; ++r) {
            p1[r] += acc[ft][r] * a1v[ft];
            p2[r] += acc[ft][r] * a2v[ft];
        }
#pragma unroll
    for (int off = 1; off < 16; off <<= 1)
#pragma unroll
        for (int r = 0; r < 4; ++r) {
            p1[r] += __shfl_xor(p1[r], off);
            p2[r] += __shfl_xor(p2[r], off);
        }
    if (l15 == 0)
#pragma unroll
        for (int r = 0; r < 4; ++r) {
            sp[0][wid][quad * 4 + r] = p1[r];
            sp[1][wid][quad * 4 + r] = p2[r];
        }
    __syncthreads();
    if (t < 16) {
        f1[m0 + t] = sp[0][0][t] + sp[0][1][t] + sp[0][2][t] + sp[0][3][t];
        f2[m0 + t] = sp[1][0][t] + sp[1][1][t] + sp[1][2][t] + sp[1][3][t];
    }
}

// ---------------------------------------------------------------------------
// stats_p: wave per row, coalesced (lane j-slice = lane*4 + 256*c, so every
// load instruction covers 1 KB contiguous). One streaming pass over adj;
// writes normalized P[b][i][j] = bf16(exp(e_ij - m_i)/l_i). No barriers.
// ---------------------------------------------------------------------------
__global__ __launch_bounds__(256) void stats_p(const int* __restrict__ adj,
                                               const float* __restrict__ f1g,
                                               const float* __restrict__ f2g,
                                               short* __restrict__ P) {
    const int wid = threadIdx.x >> 6, lane = threadIdx.x & 63;
    const int gid = blockIdx.x * 4 + wid;          // row 0..16383
    const int b = gid >> 10;
    const int* arow = adj + (size_t)gid * 1024;
    const float* f2b = f2g + (b << 10);
    const float f1r = f1g[gid];

    float e[16];
#pragma unroll
    for (int c = 0; c < 4; ++c) {
        int4 av = *(const int4*)(arow + lane * 4 + c * 256);
        float4 fv = *(const float4*)(f2b + lane * 4 + c * 256);
        float x0 = f1r + fv.x, x1 = f1r + fv.y, x2 = f1r + fv.z, x3 = f1r + fv.w;
        e[c * 4 + 0] = av.x ? fmaxf(x0, 0.2f * x0) : -3.0e38f;
        e[c * 4 + 1] = av.y ? fmaxf(x1, 0.2f * x1) : -3.0e38f;
        e[c * 4 + 2] = av.z ? fmaxf(x2, 0.2f * x2) : -3.0e38f;
        e[c * 4 + 3] = av.w ? fmaxf(x3, 0.2f * x3) : -3.0e38f;
    }
    float m = e[0];
#pragma unroll
    for (int q = 1; q < 16; ++q) m = fmaxf(m, e[q]);
#pragma unroll
    for (int off = 32; off; off >>= 1) m = fmaxf(m, __shfl_xor(m, off));

    float p[16];
    float l = 0.f;
#pragma unroll
    for (int q = 0; q < 16; ++q) { p[q] = __expf(e[q] - m); l += p[q]; }
#pragma unroll
    for (int off = 32; off; off >>= 1) l += __shfl_xor(l, off);
    const float invl = 1.0f / l;

    short* prow = P + (size_t)gid * 1024;
#pragma unroll
    for (int c = 0; c < 4; ++c) {
        ushort4 pk;
        pk.x = f2bf(p[c * 4 + 0] * invl);
        pk.y = f2bf(p[c * 4 + 1] * invl);
        pk.z = f2bf(p[c * 4 + 2] * invl);
        pk.w = f2bf(p[c * 4 + 3] * invl);
        *(ushort4*)(prow + lane * 4 + c * 256) = pk;
    }
}

// ---------------------------------------------------------------------------
// agg: out[b] = P[b] (1024x1024) @ WhT[b]^T (K-contig B). m97-style GEMM:
// 128M x 64N tile, BK=32, global_load_lds(16B) staging, 2 barriers/iter.
// Grid (8,4,16) = 512 blocks -> 2 blocks/CU.
// ---------------------------------------------------------------------------
__global__ __launch_bounds__(256, 2) void agg(const short* __restrict__ P,
                                              const short* __restrict__ WhT,
                                              float* __restrict__ out) {
    __shared__ short As[128 * 32];   // 8 KB
    __shared__ short Bs[64 * 32];    // 4 KB

    const int t = threadIdx.x;
    const int wid = t >> 6, lane = t & 63;
    const int quad = lane >> 4, l15 = lane & 15;
    const int m0 = blockIdx.x * 128, n0 = blockIdx.y * 64, b = blockIdx.z;

    const short* Pb = P + ((size_t)b << 20);
    const short* Wb = WhT + ((size_t)b << 18);

    // staging: chunk c=t -> row c>>2, short-offset (c&3)*8; lds byte = c*16
    const int ar = t >> 2, aq = (t & 3) * 8;
    const short* ga0 = Pb + (size_t)(m0 + ar) * 1024 + aq;         // As rows 0..63
    const short* ga1 = Pb + (size_t)(m0 + 64 + ar) * 1024 + aq;    // As rows 64..127
    const short* gb0 = Wb + (size_t)(n0 + ar) * 1024 + aq;         // Bs rows 0..63
    short* lA0 = As + t * 8;
    short* lA1 = As + 2048 + t * 8;
    short* lB0 = Bs + t * 8;

    f32x4 acc[2][4] = {};

    for (int k0 = 0; k0 < 1024; k0 += 32) {
        gl_lds16(ga0 + k0, lA0);
        gl_lds16(ga1 + k0, lA1);
        gl_lds16(gb0 + k0, lB0);
        __syncthreads();

        bf16x8 av[2], bv[4];
#pragma unroll
        for (int mf = 0; mf < 2; ++mf)
            av[mf] = *(const bf16x8*)(As + (wid * 32 + mf * 16 + l15) * 32 + quad * 8);
#pragma unroll
        for (int nf = 0; nf < 4; ++nf)
            bv[nf] = *(const bf16x8*)(Bs + (nf * 16 + l15) * 32 + quad * 8);
#pragma unroll
        for (int mf = 0; mf < 2; ++mf)
#pragma unroll
            for (int nf = 0; nf < 4; ++nf)
                acc[mf][nf] = __builtin_amdgcn_mfma_f32_16x16x32_bf16(av[mf], bv[nf], acc[mf][nf], 0, 0, 0);
        __syncthreads();
    }

    // epilogue: C row = quad*4+reg, col = l15 (within 16x16 frag)
#pragma unroll
    for (int mf = 0; mf < 2; ++mf) {
        const int i = m0 + wid * 32 + mf * 16 + quad * 4;
#pragma unroll
        for (int nf = 0; nf < 4; ++nf) {
            float* op = out + (size_t)((b << 10) + i) * 256 + n0 + nf * 16 + l15;
            op[0]   = acc[mf][nf][0];
            op[256] = acc[mf][nf][1];
            op[512] = acc[mf][nf][2];
            op[768] = acc[mf][nf][3];
        }
    }
}

// ---------------------------------------------------------------------------
extern "C" void kernel_launch(void* const* d_in, const int* in_sizes, int n_in,
                              void* d_out, int out_size, void* d_ws, size_t ws_size,
                              hipStream_t stream) {
    const float* h   = (const float*)d_in[0];
    const int*   adj = (const int*)d_in[1];
    const float* W   = (const float*)d_in[2];
    const float* a   = (const float*)d_in[3];
    float* out = (float*)d_out;

    short* WbT = (short*)d_ws;                       // 128 KB
    float* f1  = (float*)(WbT + 65536);              // 64 KB
    float* f2  = f1 + 16384;                         // 64 KB
    short* WhT = (short*)(f2 + 16384);               // 8 MB
    short* P   = WhT + 16 * 256 * 1024;              // 32 MB

    prep<<<64, 256, 0, stream>>>(W, WbT);
    wh_f12<<<1024, 256, 0, stream>>>(h, WbT, a, WhT, f1, f2);
    stats_p<<<4096, 256, 0, stream>>>(adj, f1, f2, P);
    agg<<<dim3(8, 4, 16), 256, 0, stream>>>(P, WhT, out);
}

// Round 8
// 152.211 us; speedup vs baseline: 1.2956x; 1.0881x over previous
//
#include <hip/hip_runtime.h>

typedef __attribute__((ext_vector_type(8))) short bf16x8;
typedef __attribute__((ext_vector_type(4))) float f32x4;

__device__ __forceinline__ unsigned short f2bf(float x) {
    unsigned int u = __float_as_uint(x);
    u += 0x7FFFu + ((u >> 16) & 1u);        // round-to-nearest-even
    return (unsigned short)(u >> 16);
}

// async global->LDS, 16B per lane; LDS dest = wave-uniform base + lane*16.
__device__ __forceinline__ void gl_lds16(const void* g, void* l) {
    __builtin_amdgcn_global_load_lds(
        (__attribute__((address_space(1))) void*)((void*)g),
        (__attribute__((address_space(3))) void*)l, 16, 0, 0);
}

// ---------------------------------------------------------------------------
// prep: WbT[n][k] = bf16(W[k][n]) via coalesced 32x32 LDS transpose. Grid 64.
// ---------------------------------------------------------------------------
__global__ __launch_bounds__(256) void prep(const float* __restrict__ W,
                                            short* __restrict__ WbT) {
    __shared__ float tile[32][33];
    const int t = threadIdx.x;
    const int bx = blockIdx.x & 7, by = blockIdx.x >> 3;
    const int r0 = by * 32, c0 = bx * 32;
    const int lr = t >> 5, lc = t & 31;
#pragma unroll
    for (int q = 0; q < 4; ++q)
        tile[q * 8 + lr][lc] = W[(r0 + q * 8 + lr) * 256 + c0 + lc];
    __syncthreads();
#pragma unroll
    for (int q = 0; q < 4; ++q)
        WbT[(c0 + q * 8 + lr) * 256 + r0 + lc] = (short)f2bf(tile[lc][q * 8 + lr]);
}

// ---------------------------------------------------------------------------
// wh_f12: 32 nodes/block (grid 512, 2 blocks/CU). B-frags reused across 2
// m-frags. WhT[b][f][j] stored bf16-transposed; f1/f2 from fp32 accumulators.
// ---------------------------------------------------------------------------
__global__ __launch_bounds__(256, 4) void wh_f12(const float* __restrict__ h,
                                                 const short* __restrict__ WbT,
                                                 const float* __restrict__ a,
                                                 short* __restrict__ WhT,
                                                 float* __restrict__ f1,
                                                 float* __restrict__ f2) {
    __shared__ short hA[32][264];      // +8 pad -> 2-way bank aliasing (free)
    __shared__ float sp[2][4][32];
    const int t = threadIdx.x;
    const int wid = t >> 6, lane = t & 63;
    const int quad = lane >> 4, l15 = lane & 15;
    const int m0 = blockIdx.x * 32;

    // --- stage h-tile (2 rows per 16-thread group; 64 B contiguous/thread)
#pragma unroll
    for (int rr = 0; rr < 2; ++rr) {
        const int r = rr * 16 + (t >> 4), c0 = (t & 15) * 16;
        const float* hp = h + (size_t)(m0 + r) * 256 + c0;
        float4 v0 = *(const float4*)(hp + 0), v1 = *(const float4*)(hp + 4);
        float4 v2 = *(const float4*)(hp + 8), v3 = *(const float4*)(hp + 12);
        bf16x8 w0, w1;
        w0[0] = (short)f2bf(v0.x); w0[1] = (short)f2bf(v0.y);
        w0[2] = (short)f2bf(v0.z); w0[3] = (short)f2bf(v0.w);
        w0[4] = (short)f2bf(v1.x); w0[5] = (short)f2bf(v1.y);
        w0[6] = (short)f2bf(v1.z); w0[7] = (short)f2bf(v1.w);
        w1[0] = (short)f2bf(v2.x); w1[1] = (short)f2bf(v2.y);
        w1[2] = (short)f2bf(v2.z); w1[3] = (short)f2bf(v2.w);
        w1[4] = (short)f2bf(v3.x); w1[5] = (short)f2bf(v3.y);
        w1[6] = (short)f2bf(v3.z); w1[7] = (short)f2bf(v3.w);
        *(bf16x8*)&hA[r][c0] = w0;
        *(bf16x8*)&hA[r][c0 + 8] = w1;
    }
    __syncthreads();

    f32x4 acc[2][4] = {};
#pragma unroll
    for (int kt = 0; kt < 8; ++kt) {
        const int k0 = kt * 32;
        bf16x8 bv[4];
#pragma unroll
        for (int ft = 0; ft < 4; ++ft)
            bv[ft] = *(const bf16x8*)(WbT + (size_t)(wid * 64 + ft * 16 + l15) * 256 + k0 + quad * 8);
        bf16x8 a0 = *(const bf16x8*)&hA[l15][k0 + quad * 8];
        bf16x8 a1 = *(const bf16x8*)&hA[16 + l15][k0 + quad * 8];
#pragma unroll
        for (int ft = 0; ft < 4; ++ft) {
            acc[0][ft] = __builtin_amdgcn_mfma_f32_16x16x32_bf16(a0, bv[ft], acc[0][ft], 0, 0, 0);
            acc[1][ft] = __builtin_amdgcn_mfma_f32_16x16x32_bf16(a1, bv[ft], acc[1][ft], 0, 0, 0);
        }
    }

    // --- WhT store (C row = quad*4+reg, col f = wid*64+ft*16+l15)
    const int b = m0 >> 10;
#pragma unroll
    for (int mf = 0; mf < 2; ++mf) {
        const int il0 = (m0 & 1023) + mf * 16 + quad * 4;
#pragma unroll
        for (int ft = 0; ft < 4; ++ft) {
            const int f = wid * 64 + ft * 16 + l15;
            ushort4 pk;
            pk.x = f2bf(acc[mf][ft][0]);
            pk.y = f2bf(acc[mf][ft][1]);
            pk.z = f2bf(acc[mf][ft][2]);
            pk.w = f2bf(acc[mf][ft][3]);
            *(ushort4*)(WhT + ((size_t)b << 18) + (size_t)f * 1024 + il0) = pk;
        }
    }

    // --- f1/f2 from fp32 acc: dot with a1/a2 over this wave's 64-f slice
    float a1v[4], a2v[4];
#pragma unroll
    for (int ft = 0; ft < 4; ++ft) {
        a1v[ft] = a[wid * 64 + ft * 16 + l15];
        a2v[ft] = a[256 + wid * 64 + ft * 16 + l15];
    }
    float p1[2][4] = {}, p2[2][4] = {};
#pragma unroll
    for (int mf = 0; mf < 2; ++mf)
#pragma unroll
        for (int ft = 0; ft < 4; ++ft)
#pragma unroll
            for (int r = 0; r < 4; ++r) {
                p1[mf][r] += acc[mf][ft][r] * a1v[ft];
                p2[mf][r] += acc[mf][ft][r] * a2v[ft];
            }
#pragma unroll
    for (int off = 1; off < 16; off <<= 1)
#pragma unroll
        for (int mf = 0; mf < 2; ++mf)
#pragma unroll
            for (int r = 0; r < 4; ++r) {
                p1[mf][r] += __shfl_xor(p1[mf][r], off);
                p2[mf][r] += __shfl_xor(p2[mf][r], off);
            }
    if (l15 == 0)
#pragma unroll
        for (int mf = 0; mf < 2; ++mf)
#pragma unroll
            for (int r = 0; r < 4; ++r) {
                sp[0][wid][mf * 16 + quad * 4 + r] = p1[mf][r];
                sp[1][wid][mf * 16 + quad * 4 + r] = p2[mf][r];
            }
    __syncthreads();
    if (t < 32) {
        f1[m0 + t] = sp[0][0][t] + sp[0][1][t] + sp[0][2][t] + sp[0][3][t];
        f2[m0 + t] = sp[1][0][t] + sp[1][1][t] + sp[1][2][t] + sp[1][3][t];
    }
}

// ---------------------------------------------------------------------------
// stats_p: wave per row, coalesced (every load instr covers 1 KB contiguous).
// One streaming pass over adj; writes normalized P = bf16(exp(e-m)/l).
// ---------------------------------------------------------------------------
__global__ __launch_bounds__(256) void stats_p(const int* __restrict__ adj,
                                               const float* __restrict__ f1g,
                                               const float* __restrict__ f2g,
                                               short* __restrict__ P) {
    const int wid = threadIdx.x >> 6, lane = threadIdx.x & 63;
    const int gid = blockIdx.x * 4 + wid;          // row 0..16383
    const int b = gid >> 10;
    const int* arow = adj + (size_t)gid * 1024;
    const float* f2b = f2g + (b << 10);
    const float f1r = f1g[gid];

    float e[16];
#pragma unroll
    for (int c = 0; c < 4; ++c) {
        int4 av = *(const int4*)(arow + lane * 4 + c * 256);
        float4 fv = *(const float4*)(f2b + lane * 4 + c * 256);
        float x0 = f1r + fv.x, x1 = f1r + fv.y, x2 = f1r + fv.z, x3 = f1r + fv.w;
        e[c * 4 + 0] = av.x ? fmaxf(x0, 0.2f * x0) : -3.0e38f;
        e[c * 4 + 1] = av.y ? fmaxf(x1, 0.2f * x1) : -3.0e38f;
        e[c * 4 + 2] = av.z ? fmaxf(x2, 0.2f * x2) : -3.0e38f;
        e[c * 4 + 3] = av.w ? fmaxf(x3, 0.2f * x3) : -3.0e38f;
    }
    float m = e[0];
#pragma unroll
    for (int q = 1; q < 16; ++q) m = fmaxf(m, e[q]);
#pragma unroll
    for (int off = 32; off; off >>= 1) m = fmaxf(m, __shfl_xor(m, off));

    float p[16];
    float l = 0.f;
#pragma unroll
    for (int q = 0; q < 16; ++q) { p[q] = __expf(e[q] - m); l += p[q]; }
#pragma unroll
    for (int off = 32; off; off >>= 1) l += __shfl_xor(l, off);
    const float invl = 1.0f / l;

    short* prow = P + (size_t)gid * 1024;
#pragma unroll
    for (int c = 0; c < 4; ++c) {
        ushort4 pk;
        pk.x = f2bf(p[c * 4 + 0] * invl);
        pk.y = f2bf(p[c * 4 + 1] * invl);
        pk.z = f2bf(p[c * 4 + 2] * invl);
        pk.w = f2bf(p[c * 4 + 3] * invl);
        *(ushort4*)(prow + lane * 4 + c * 256) = pk;
    }
}

// ---------------------------------------------------------------------------
// agg: out[b] = P[b] @ WhT[b]^T. 64x64 tile, BK=64, grid (16,4,16)=1024
// -> 4 blocks/CU. gl_lds staging with XOR chunk swizzle: row r's 16B chunk w
// lives at LDS slot (w ^ (r&7)) -> frag ds_read_b128 spreads over all 32
// banks (2-way aliasing = free) while global reads stay 128B-coalesced.
// ---------------------------------------------------------------------------
__global__ __launch_bounds__(256, 4) void agg(const short* __restrict__ P,
                                              const short* __restrict__ WhT,
                                              float* __restrict__ out) {
    __shared__ short As[64 * 64];   // 8 KB
    __shared__ short Bs[64 * 64];   // 8 KB

    const int t = threadIdx.x;
    const int wid = t >> 6, lane = t & 63;
    const int quad = lane >> 4, l15 = lane & 15;
    const int m0 = blockIdx.x * 64, n0 = blockIdx.y * 64, b = blockIdx.z;

    const short* Pb = P + ((size_t)b << 20);
    const short* Wb = WhT + ((size_t)b << 18);

    // staging: LDS chunk c (16B) -> row c>>3, slot c&7; global chunk w = slot ^ (row&7)
    const int r0 = t >> 3;                 // rows 0..31  (chunk c = t)
    const int w0 = (t & 7) ^ (r0 & 7);
    const short* gaA0 = Pb + (size_t)(m0 + r0) * 1024 + w0 * 8;       // rows 0..31
    const short* gaA1 = Pb + (size_t)(m0 + 32 + r0) * 1024 + w0 * 8;  // rows 32..63
    const short* gaB0 = Wb + (size_t)(n0 + r0) * 1024 + w0 * 8;
    const short* gaB1 = Wb + (size_t)(n0 + 32 + r0) * 1024 + w0 * 8;
    short* lA0 = As + t * 8;
    short* lA1 = As + 2048 + t * 8;
    short* lB0 = Bs + t * 8;
    short* lB1 = Bs + 2048 + t * 8;

    f32x4 acc[4] = {};
    const int ra = wid * 16 + l15;         // A row this lane reads (m)

    for (int k0 = 0; k0 < 1024; k0 += 64) {
        gl_lds16(gaA0 + k0, lA0);
        gl_lds16(gaA1 + k0, lA1);
        gl_lds16(gaB0 + k0, lB0);
        gl_lds16(gaB1 + k0, lB1);
        __syncthreads();

#pragma unroll
        for (int kt = 0; kt < 2; ++kt) {
            const int w = kt * 4 + quad;
            bf16x8 av = *(const bf16x8*)(As + ra * 64 + ((w ^ (ra & 7)) * 8));
#pragma unroll
            for (int nf = 0; nf < 4; ++nf) {
                const int rb = nf * 16 + l15;
                bf16x8 bv = *(const bf16x8*)(Bs + rb * 64 + ((w ^ (rb & 7)) * 8));
                acc[nf] = __builtin_amdgcn_mfma_f32_16x16x32_bf16(av, bv, acc[nf], 0, 0, 0);
            }
        }
        __syncthreads();
    }

    // epilogue: C row = quad*4+reg (within wave's 16-m slice), col = l15
    const int i = m0 + wid * 16 + quad * 4;
#pragma unroll
    for (int nf = 0; nf < 4; ++nf) {
        float* op = out + (size_t)((b << 10) + i) * 256 + n0 + nf * 16 + l15;
        op[0]   = acc[nf][0];
        op[256] = acc[nf][1];
        op[512] = acc[nf][2];
        op[768] = acc[nf][3];
    }
}

// ---------------------------------------------------------------------------
extern "C" void kernel_launch(void* const* d_in, const int* in_sizes, int n_in,
                              void* d_out, int out_size, void* d_ws, size_t ws_size,
                              hipStream_t stream) {
    const float* h   = (const float*)d_in[0];
    const int*   adj = (const int*)d_in[1];
    const float* W   = (const float*)d_in[2];
    const float* a   = (const float*)d_in[3];
    float* out = (float*)d_out;

    short* WbT = (short*)d_ws;                       // 128 KB
    float* f1  = (float*)(WbT + 65536);              // 64 KB
    float* f2  = f1 + 16384;                         // 64 KB
    short* WhT = (short*)(f2 + 16384);               // 8 MB
    short* P   = WhT + 16 * 256 * 1024;              // 32 MB

    prep<<<64, 256, 0, stream>>>(W, WbT);
    wh_f12<<<512, 256, 0, stream>>>(h, WbT, a, WhT, f1, f2);
    stats_p<<<4096, 256, 0, stream>>>(adj, f1, f2, P);
    agg<<<dim3(16, 4, 16), 256, 0, stream>>>(P, WhT, out);
}

// Round 9
// 151.962 us; speedup vs baseline: 1.2978x; 1.0016x over previous
//
#include <hip/hip_runtime.h>

typedef __attribute__((ext_vector_type(8))) short bf16x8;
typedef __attribute__((ext_vector_type(4))) float f32x4;

__device__ __forceinline__ unsigned short f2bf(float x) {
    unsigned int u = __float_as_uint(x);
    u += 0x7FFFu + ((u >> 16) & 1u);        // round-to-nearest-even
    return (unsigned short)(u >> 16);
}

// async global->LDS, 16B per lane; LDS dest = wave-uniform base + lane*16.
__device__ __forceinline__ void gl_lds16(const void* g, void* l) {
    __builtin_amdgcn_global_load_lds(
        (__attribute__((address_space(1))) void*)((void*)g),
        (__attribute__((address_space(3))) void*)l, 16, 0, 0);
}

// ---------------------------------------------------------------------------
// prep: WbT[n][k] = bf16(W[k][n]) via coalesced 32x32 LDS transpose. Grid 64.
// ---------------------------------------------------------------------------
__global__ __launch_bounds__(256) void prep(const float* __restrict__ W,
                                            short* __restrict__ WbT) {
    __shared__ float tile[32][33];
    const int t = threadIdx.x;
    const int bx = blockIdx.x & 7, by = blockIdx.x >> 3;
    const int r0 = by * 32, c0 = bx * 32;
    const int lr = t >> 5, lc = t & 31;
#pragma unroll
    for (int q = 0; q < 4; ++q)
        tile[q * 8 + lr][lc] = W[(r0 + q * 8 + lr) * 256 + c0 + lc];
    __syncthreads();
#pragma unroll
    for (int q = 0; q < 4; ++q)
        WbT[(c0 + q * 8 + lr) * 256 + r0 + lc] = (short)f2bf(tile[lc][q * 8 + lr]);
}

// ---------------------------------------------------------------------------
// wh_f12: 32 nodes/block (grid 512). B-frags reused across 2 m-frags.
// WhT[b][f][j] stored bf16-transposed; f1/f2 from fp32 accumulators.
// ---------------------------------------------------------------------------
__global__ __launch_bounds__(256, 4) void wh_f12(const float* __restrict__ h,
                                                 const short* __restrict__ WbT,
                                                 const float* __restrict__ a,
                                                 short* __restrict__ WhT,
                                                 float* __restrict__ f1,
                                                 float* __restrict__ f2) {
    __shared__ short hA[32][264];      // +8 pad -> 2-way bank aliasing (free)
    __shared__ float sp[2][4][32];
    const int t = threadIdx.x;
    const int wid = t >> 6, lane = t & 63;
    const int quad = lane >> 4, l15 = lane & 15;
    const int m0 = blockIdx.x * 32;

    // --- stage h-tile (2 rows per 16-thread group; 64 B contiguous/thread)
#pragma unroll
    for (int rr = 0; rr < 2; ++rr) {
        const int r = rr * 16 + (t >> 4), c0 = (t & 15) * 16;
        const float* hp = h + (size_t)(m0 + r) * 256 + c0;
        float4 v0 = *(const float4*)(hp + 0), v1 = *(const float4*)(hp + 4);
        float4 v2 = *(const float4*)(hp + 8), v3 = *(const float4*)(hp + 12);
        bf16x8 w0, w1;
        w0[0] = (short)f2bf(v0.x); w0[1] = (short)f2bf(v0.y);
        w0[2] = (short)f2bf(v0.z); w0[3] = (short)f2bf(v0.w);
        w0[4] = (short)f2bf(v1.x); w0[5] = (short)f2bf(v1.y);
        w0[6] = (short)f2bf(v1.z); w0[7] = (short)f2bf(v1.w);
        w1[0] = (short)f2bf(v2.x); w1[1] = (short)f2bf(v2.y);
        w1[2] = (short)f2bf(v2.z); w1[3] = (short)f2bf(v2.w);
        w1[4] = (short)f2bf(v3.x); w1[5] = (short)f2bf(v3.y);
        w1[6] = (short)f2bf(v3.z); w1[7] = (short)f2bf(v3.w);
        *(bf16x8*)&hA[r][c0] = w0;
        *(bf16x8*)&hA[r][c0 + 8] = w1;
    }
    __syncthreads();

    f32x4 acc[2][4] = {};
#pragma unroll
    for (int kt = 0; kt < 8; ++kt) {
        const int k0 = kt * 32;
        bf16x8 bv[4];
#pragma unroll
        for (int ft = 0; ft < 4; ++ft)
            bv[ft] = *(const bf16x8*)(WbT + (size_t)(wid * 64 + ft * 16 + l15) * 256 + k0 + quad * 8);
        bf16x8 a0 = *(const bf16x8*)&hA[l15][k0 + quad * 8];
        bf16x8 a1 = *(const bf16x8*)&hA[16 + l15][k0 + quad * 8];
#pragma unroll
        for (int ft = 0; ft < 4; ++ft) {
            acc[0][ft] = __builtin_amdgcn_mfma_f32_16x16x32_bf16(a0, bv[ft], acc[0][ft], 0, 0, 0);
            acc[1][ft] = __builtin_amdgcn_mfma_f32_16x16x32_bf16(a1, bv[ft], acc[1][ft], 0, 0, 0);
        }
    }

    // --- WhT store (C row = quad*4+reg, col f = wid*64+ft*16+l15)
    const int b = m0 >> 10;
#pragma unroll
    for (int mf = 0; mf < 2; ++mf) {
        const int il0 = (m0 & 1023) + mf * 16 + quad * 4;
#pragma unroll
        for (int ft = 0; ft < 4; ++ft) {
            const int f = wid * 64 + ft * 16 + l15;
            ushort4 pk;
            pk.x = f2bf(acc[mf][ft][0]);
            pk.y = f2bf(acc[mf][ft][1]);
            pk.z = f2bf(acc[mf][ft][2]);
            pk.w = f2bf(acc[mf][ft][3]);
            *(ushort4*)(WhT + ((size_t)b << 18) + (size_t)f * 1024 + il0) = pk;
        }
    }

    // --- f1/f2 from fp32 acc: dot with a1/a2 over this wave's 64-f slice
    float a1v[4], a2v[4];
#pragma unroll
    for (int ft = 0; ft < 4; ++ft) {
        a1v[ft] = a[wid * 64 + ft * 16 + l15];
        a2v[ft] = a[256 + wid * 64 + ft * 16 + l15];
    }
    float p1[2][4] = {}, p2[2][4] = {};
#pragma unroll
    for (int mf = 0; mf < 2; ++mf)
#pragma unroll
        for (int ft = 0; ft < 4; ++ft)
#pragma unroll
            for (int r = 0; r < 4; ++r) {
                p1[mf][r] += acc[mf][ft][r] * a1v[ft];
                p2[mf][r] += acc[mf][ft][r] * a2v[ft];
            }
#pragma unroll
    for (int off = 1; off < 16; off <<= 1)
#pragma unroll
        for (int mf = 0; mf < 2; ++mf)
#pragma unroll
            for (int r = 0; r < 4; ++r) {
                p1[mf][r] += __shfl_xor(p1[mf][r], off);
                p2[mf][r] += __shfl_xor(p2[mf][r], off);
            }
    if (l15 == 0)
#pragma unroll
        for (int mf = 0; mf < 2; ++mf)
#pragma unroll
            for (int r = 0; r < 4; ++r) {
                sp[0][wid][mf * 16 + quad * 4 + r] = p1[mf][r];
                sp[1][wid][mf * 16 + quad * 4 + r] = p2[mf][r];
            }
    __syncthreads();
    if (t < 32) {
        f1[m0 + t] = sp[0][0][t] + sp[0][1][t] + sp[0][2][t] + sp[0][3][t];
        f2[m0 + t] = sp[1][0][t] + sp[1][1][t] + sp[1][2][t] + sp[1][3][t];
    }
}

// ---------------------------------------------------------------------------
// stats_p: wave per row, coalesced (every load instr covers 1 KB contiguous).
// One streaming pass over adj; writes normalized P = bf16(exp(e-m)/l).
// ---------------------------------------------------------------------------
__global__ __launch_bounds__(256) void stats_p(const int* __restrict__ adj,
                                               const float* __restrict__ f1g,
                                               const float* __restrict__ f2g,
                                               short* __restrict__ P) {
    const int wid = threadIdx.x >> 6, lane = threadIdx.x & 63;
    const int gid = blockIdx.x * 4 + wid;          // row 0..16383
    const int b = gid >> 10;
    const int* arow = adj + (size_t)gid * 1024;
    const float* f2b = f2g + (b << 10);
    const float f1r = f1g[gid];

    float e[16];
#pragma unroll
    for (int c = 0; c < 4; ++c) {
        int4 av = *(const int4*)(arow + lane * 4 + c * 256);
        float4 fv = *(const float4*)(f2b + lane * 4 + c * 256);
        float x0 = f1r + fv.x, x1 = f1r + fv.y, x2 = f1r + fv.z, x3 = f1r + fv.w;
        e[c * 4 + 0] = av.x ? fmaxf(x0, 0.2f * x0) : -3.0e38f;
        e[c * 4 + 1] = av.y ? fmaxf(x1, 0.2f * x1) : -3.0e38f;
        e[c * 4 + 2] = av.z ? fmaxf(x2, 0.2f * x2) : -3.0e38f;
        e[c * 4 + 3] = av.w ? fmaxf(x3, 0.2f * x3) : -3.0e38f;
    }
    float m = e[0];
#pragma unroll
    for (int q = 1; q < 16; ++q) m = fmaxf(m, e[q]);
#pragma unroll
    for (int off = 32; off; off >>= 1) m = fmaxf(m, __shfl_xor(m, off));

    float p[16];
    float l = 0.f;
#pragma unroll
    for (int q = 0; q < 16; ++q) { p[q] = __expf(e[q] - m); l += p[q]; }
#pragma unroll
    for (int off = 32; off; off >>= 1) l += __shfl_xor(l, off);
    const float invl = 1.0f / l;

    short* prow = P + (size_t)gid * 1024;
#pragma unroll
    for (int c = 0; c < 4; ++c) {
        ushort4 pk;
        pk.x = f2bf(p[c * 4 + 0] * invl);
        pk.y = f2bf(p[c * 4 + 1] * invl);
        pk.z = f2bf(p[c * 4 + 2] * invl);
        pk.w = f2bf(p[c * 4 + 3] * invl);
        *(ushort4*)(prow + lane * 4 + c * 256) = pk;
    }
}

// ---------------------------------------------------------------------------
// agg: out[b] = P[b] @ WhT[b]^T. Block tile 64m x 128n, BK=64; wave tile
// 32m x 64n (12 ds_read_b128 per 16 MFMA). XOR chunk swizzle in LDS (2-way
// bank aliasing = free, global reads stay 128B-coalesced). 1D grid 512 with
// XCD decode (b % 8 == blockIdx % 8): both batches' WhT (1 MB) pin in the
// local 4 MB L2; P n-pair reuse is L2-local. 2 blocks/CU, all co-resident.
// ---------------------------------------------------------------------------
__global__ __launch_bounds__(256, 4) void agg(const short* __restrict__ P,
                                              const short* __restrict__ WhT,
                                              float* __restrict__ out) {
    __shared__ short As[64 * 64];    // 8 KB
    __shared__ short Bs[128 * 64];   // 16 KB

    const int t = threadIdx.x;
    const int wid = t >> 6, lane = t & 63;
    const int quad = lane >> 4, l15 = lane & 15;

    // XCD-aware decode: xcd = id&7, b = xcd + 8*(rest&1), n = (rest>>1)&1, m = rest>>2
    const int id = blockIdx.x;
    const int xcd = id & 7, rest = id >> 3;
    const int b = xcd + 8 * (rest & 1);
    const int n0 = ((rest >> 1) & 1) * 128;
    const int m0 = (rest >> 2) * 64;

    const short* Pb = P + ((size_t)b << 20);
    const short* Wb = WhT + ((size_t)b << 18);

    // staging: LDS chunk c (16B) -> row c>>3, slot c&7; global chunk = slot ^ (row&7)
    const int rA = t >> 3, wA = (t & 7) ^ (rA & 7);          // A chunks c=t, t+256
    const short* gA0 = Pb + (size_t)(m0 + rA) * 1024 + wA * 8;
    const short* gA1 = Pb + (size_t)(m0 + 32 + rA) * 1024 + wA * 8;
    const short* gB0 = Wb + (size_t)(n0 + rA) * 1024 + wA * 8;        // B c=t..t+768
    const short* gB1 = Wb + (size_t)(n0 + 32 + rA) * 1024 + wA * 8;
    const short* gB2 = Wb + (size_t)(n0 + 64 + rA) * 1024 + wA * 8;
    const short* gB3 = Wb + (size_t)(n0 + 96 + rA) * 1024 + wA * 8;
    short* lA0 = As + t * 8;
    short* lA1 = As + 2048 + t * 8;
    short* lB0 = Bs + t * 8;
    short* lB1 = Bs + 2048 + t * 8;
    short* lB2 = Bs + 4096 + t * 8;
    short* lB3 = Bs + 6144 + t * 8;

    const int mh = (wid & 1) * 32;      // wave m-half
    const int nq = (wid >> 1) * 64;     // wave n-quarter

    f32x4 acc[2][4] = {};

    for (int k0 = 0; k0 < 1024; k0 += 64) {
        gl_lds16(gA0 + k0, lA0);
        gl_lds16(gA1 + k0, lA1);
        gl_lds16(gB0 + k0, lB0);
        gl_lds16(gB1 + k0, lB1);
        gl_lds16(gB2 + k0, lB2);
        gl_lds16(gB3 + k0, lB3);
        __syncthreads();

#pragma unroll
        for (int kt = 0; kt < 2; ++kt) {
            const int w = kt * 4 + quad;
            bf16x8 av[2], bv[4];
#pragma unroll
            for (int mf = 0; mf < 2; ++mf) {
                const int r = mh + mf * 16 + l15;
                av[mf] = *(const bf16x8*)(As + r * 64 + ((w ^ (r & 7)) * 8));
            }
#pragma unroll
            for (int nf = 0; nf < 4; ++nf) {
                const int r = nq + nf * 16 + l15;
                bv[nf] = *(const bf16x8*)(Bs + r * 64 + ((w ^ (r & 7)) * 8));
            }
#pragma unroll
            for (int mf = 0; mf < 2; ++mf)
#pragma unroll
                for (int nf = 0; nf < 4; ++nf)
                    acc[mf][nf] = __builtin_amdgcn_mfma_f32_16x16x32_bf16(av[mf], bv[nf], acc[mf][nf], 0, 0, 0);
        }
        __syncthreads();
    }

    // epilogue: C row = quad*4+reg, col = l15
#pragma unroll
    for (int mf = 0; mf < 2; ++mf) {
        const int i = m0 + mh + mf * 16 + quad * 4;
#pragma unroll
        for (int nf = 0; nf < 4; ++nf) {
            float* op = out + (size_t)((b << 10) + i) * 256 + n0 + nq + nf * 16 + l15;
            op[0]   = acc[mf][nf][0];
            op[256] = acc[mf][nf][1];
            op[512] = acc[mf][nf][2];
            op[768] = acc[mf][nf][3];
        }
    }
}

// ---------------------------------------------------------------------------
extern "C" void kernel_launch(void* const* d_in, const int* in_sizes, int n_in,
                              void* d_out, int out_size, void* d_ws, size_t ws_size,
                              hipStream_t stream) {
    const float* h   = (const float*)d_in[0];
    const int*   adj = (const int*)d_in[1];
    const float* W   = (const float*)d_in[2];
    const float* a   = (const float*)d_in[3];
    float* out = (float*)d_out;

    short* WbT = (short*)d_ws;                       // 128 KB
    float* f1  = (float*)(WbT + 65536);              // 64 KB
    float* f2  = f1 + 16384;                         // 64 KB
    short* WhT = (short*)(f2 + 16384);               // 8 MB
    short* P   = WhT + 16 * 256 * 1024;              // 32 MB

    prep<<<64, 256, 0, stream>>>(W, WbT);
    wh_f12<<<512, 256, 0, stream>>>(h, WbT, a, WhT, f1, f2);
    stats_p<<<4096, 256, 0, stream>>>(adj, f1, f2, P);
    agg<<<512, 256, 0, stream>>>(P, WhT, out);
}